// Round 1
// baseline (309.116 us; speedup 1.0000x reference)
//
#include <hip/hip_runtime.h>
#include <cmath>

// Problem constants (from reference): N=2, Lq=Lk=1024, H=8, d=64, P=1, D=512
#define NB    2
#define LSEQ  1024
#define NH    8
#define HD    64
#define DD    512    // NH*HD
#define FDIM  128    // 2*HD  (cos|sin features)
#define EV    65     // HD + 1 (values + denominator unit column)
#define CHUNK 64
#define NC    16     // LSEQ / CHUNK
#define NBH   16     // NB*NH

__device__ __forceinline__ float softplusf(float x) {
  // jax.nn.softplus == logaddexp(x, 0) == max(x,0) + log1p(exp(-|x|))
  return fmaxf(x, 0.0f) + log1pf(expf(-fabsf(x)));
}

// ---------------------------------------------------------------------------
// K1: q projection GEMM + softplus + Fourier feature expansion
// Qf[(n*NH+h)*LSEQ + l][j]    = softplus(q)*cos(l*pw+pb)*coeff
// Qf[(n*NH+h)*LSEQ + l][64+j] = softplus(q)*sin(l*pw+pb)*coeff
// C[m,e] = sum_d X[m,d] * Wq[e,d]   (both K-major)
// ---------------------------------------------------------------------------
__global__ __launch_bounds__(256) void k_proj_q(
    const float* __restrict__ X, const float* __restrict__ Wq,
    const float* __restrict__ pw, const float* __restrict__ pb,
    const float* __restrict__ pc, float* __restrict__ Qf)
{
  __shared__ float As[16][64];  // [k][m] transposed for float4 fragment reads
  __shared__ float Bs[16][64];  // [k][e]
  const int m0 = (blockIdx.x >> 3) << 6;   // 32 m-tiles
  const int e0 = (blockIdx.x & 7) << 6;    // 8 e-tiles
  const int tid = threadIdx.x;
  const int ty = tid >> 4, tx = tid & 15;
  const int srow = tid >> 2;               // 0..63 staging row
  const int sc4  = (tid & 3) << 2;         // 0,4,8,12 staging k-offset
  float acc[4][4] = {};
  const float* Arow = &X [(size_t)(m0 + srow) * DD + sc4];
  const float* Brow = &Wq[(size_t)(e0 + srow) * DD + sc4];
  for (int k0 = 0; k0 < DD; k0 += 16) {
    const float4 a = *(const float4*)(Arow + k0);
    const float4 b = *(const float4*)(Brow + k0);
    __syncthreads();
    As[sc4+0][srow] = a.x; As[sc4+1][srow] = a.y; As[sc4+2][srow] = a.z; As[sc4+3][srow] = a.w;
    Bs[sc4+0][srow] = b.x; Bs[sc4+1][srow] = b.y; Bs[sc4+2][srow] = b.z; Bs[sc4+3][srow] = b.w;
    __syncthreads();
#pragma unroll
    for (int kk = 0; kk < 16; ++kk) {
      const float4 a4 = *(const float4*)&As[kk][ty << 2];
      const float4 b4 = *(const float4*)&Bs[kk][tx << 2];
      const float av[4] = {a4.x, a4.y, a4.z, a4.w};
      const float bv[4] = {b4.x, b4.y, b4.z, b4.w};
#pragma unroll
      for (int i = 0; i < 4; ++i)
#pragma unroll
        for (int j = 0; j < 4; ++j)
          acc[i][j] = fmaf(av[i], bv[j], acc[i][j]);
    }
  }
#pragma unroll
  for (int i = 0; i < 4; ++i) {
    const int m = m0 + (ty << 2) + i;
    const int n = m >> 10;
    const int l = m & 1023;
#pragma unroll
    for (int j = 0; j < 4; ++j) {
      const int e  = e0 + (tx << 2) + j;
      const int h  = e >> 6;
      const int jj = e & 63;
      const float v = softplusf(acc[i][j]);
      float sn, cs;
      sincosf(fmaf((float)l, pw[e], pb[e]), &sn, &cs);
      const float vc = v * pc[e];
      float* dst = &Qf[((size_t)(n * NH + h) * LSEQ + l) * FDIM + jj];
      dst[0]  = vc * cs;
      dst[64] = vc * sn;
    }
  }
}

// ---------------------------------------------------------------------------
// K2: k and v projections. e-tiles 0..7 -> Wk path (softplus+features->Kf),
// e-tiles 8..15 -> Wv path (plain -> Vx).
// ---------------------------------------------------------------------------
__global__ __launch_bounds__(256) void k_proj_kv(
    const float* __restrict__ X, const float* __restrict__ Wk,
    const float* __restrict__ Wv, const float* __restrict__ pw,
    float* __restrict__ Kf, float* __restrict__ Vx)
{
  __shared__ float As[16][64];
  __shared__ float Bs[16][64];
  const int m0 = (blockIdx.x >> 4) << 6;   // 32 m-tiles
  const int nt = blockIdx.x & 15;          // 16 e-tiles (8 for Wk, 8 for Wv)
  const int e0 = nt << 6;
  const bool vmode = (e0 >= DD);
  const float* W = vmode ? (Wv + (size_t)(e0 - DD) * DD) : (Wk + (size_t)e0 * DD);
  const int tid = threadIdx.x;
  const int ty = tid >> 4, tx = tid & 15;
  const int srow = tid >> 2;
  const int sc4  = (tid & 3) << 2;
  float acc[4][4] = {};
  const float* Arow = &X[(size_t)(m0 + srow) * DD + sc4];
  const float* Brow = &W[(size_t)srow * DD + sc4];
  for (int k0 = 0; k0 < DD; k0 += 16) {
    const float4 a = *(const float4*)(Arow + k0);
    const float4 b = *(const float4*)(Brow + k0);
    __syncthreads();
    As[sc4+0][srow] = a.x; As[sc4+1][srow] = a.y; As[sc4+2][srow] = a.z; As[sc4+3][srow] = a.w;
    Bs[sc4+0][srow] = b.x; Bs[sc4+1][srow] = b.y; Bs[sc4+2][srow] = b.z; Bs[sc4+3][srow] = b.w;
    __syncthreads();
#pragma unroll
    for (int kk = 0; kk < 16; ++kk) {
      const float4 a4 = *(const float4*)&As[kk][ty << 2];
      const float4 b4 = *(const float4*)&Bs[kk][tx << 2];
      const float av[4] = {a4.x, a4.y, a4.z, a4.w};
      const float bv[4] = {b4.x, b4.y, b4.z, b4.w};
#pragma unroll
      for (int i = 0; i < 4; ++i)
#pragma unroll
        for (int j = 0; j < 4; ++j)
          acc[i][j] = fmaf(av[i], bv[j], acc[i][j]);
    }
  }
#pragma unroll
  for (int i = 0; i < 4; ++i) {
    const int m = m0 + (ty << 2) + i;
    const int n = m >> 10;
    const int l = m & 1023;
#pragma unroll
    for (int j = 0; j < 4; ++j) {
      if (!vmode) {
        const int e  = e0 + (tx << 2) + j;
        const int h  = e >> 6;
        const int jj = e & 63;
        const float v = softplusf(acc[i][j]);
        float sn, cs;
        sincosf((float)l * pw[e], &sn, &cs);
        float* dst = &Kf[((size_t)(n * NH + h) * LSEQ + l) * FDIM + jj];
        dst[0]  = v * cs;
        dst[64] = v * sn;
      } else {
        const int e  = e0 - DD + (tx << 2) + j;
        const int h  = e >> 6;
        const int jj = e & 63;
        Vx[((size_t)(n * NH + h) * LSEQ + l) * HD + jj] = acc[i][j];
      }
    }
  }
}

// ---------------------------------------------------------------------------
// K3: per-chunk state sums. S[bh*NC+c][f][e] = sum_{t in chunk} Kf[t][f]*Vext[t][e]
// where Vext[:,64] = 1 (denominator column).
// ---------------------------------------------------------------------------
__global__ __launch_bounds__(256) void k_chunk_sums(
    const float* __restrict__ Kf, const float* __restrict__ Vx,
    float* __restrict__ S)
{
  const int c  = blockIdx.x & (NC - 1);
  const int bh = blockIdx.x >> 4;
  const int t0 = c * CHUNK;
  const int tid = threadIdx.x;
  __shared__ float Ks[CHUNK][FDIM];  // 32 KB
  __shared__ float Vs[CHUNK][HD];    // 16 KB
  for (int i = tid; i < CHUNK * (FDIM / 4); i += 256) {
    const int r = i >> 5, c4 = (i & 31) << 2;
    *(float4*)&Ks[r][c4] = *(const float4*)&Kf[((size_t)bh * LSEQ + t0 + r) * FDIM + c4];
  }
  for (int i = tid; i < CHUNK * (HD / 4); i += 256) {
    const int r = i >> 4, c4 = (i & 15) << 2;
    *(float4*)&Vs[r][c4] = *(const float4*)&Vx[((size_t)bh * LSEQ + t0 + r) * HD + c4];
  }
  __syncthreads();
  float* Sb = &S[(size_t)blockIdx.x * FDIM * EV];
  for (int task = tid; task < 32 * 17; task += 256) {
    const int ft = task & 31;          // f-tile (4 wide)
    const int et = task >> 5;          // e-tile (4 wide), et==16 -> unit column
    const int f0 = ft << 2;
    if (et == 16) {
      float s[4] = {};
      for (int t = 0; t < CHUNK; ++t) {
        const float4 k4 = *(const float4*)&Ks[t][f0];
        s[0] += k4.x; s[1] += k4.y; s[2] += k4.z; s[3] += k4.w;
      }
#pragma unroll
      for (int u = 0; u < 4; ++u) Sb[(f0 + u) * EV + 64] = s[u];
    } else {
      const int e0 = et << 2;
      float a[4][4] = {};
      for (int t = 0; t < CHUNK; ++t) {
        const float4 k4 = *(const float4*)&Ks[t][f0];
        const float4 v4 = *(const float4*)&Vs[t][e0];
        const float kv[4] = {k4.x, k4.y, k4.z, k4.w};
        const float vv[4] = {v4.x, v4.y, v4.z, v4.w};
#pragma unroll
        for (int i = 0; i < 4; ++i)
#pragma unroll
          for (int j = 0; j < 4; ++j)
            a[i][j] = fmaf(kv[i], vv[j], a[i][j]);
      }
#pragma unroll
      for (int i = 0; i < 4; ++i)
#pragma unroll
        for (int j = 0; j < 4; ++j)
          Sb[(f0 + i) * EV + e0 + j] = a[i][j];
    }
  }
}

// ---------------------------------------------------------------------------
// K4: per-chunk output.
//   P   = exclusive prefix of chunk states (summed on the fly into LDS)
//   Sc  = tril(Qf_chunk @ Kf_chunk^T)          (LDS)
//   out = (Qf@P + Sc@Vext);  attn = num/den;  scatter to (n,l,h*64+e)
// ---------------------------------------------------------------------------
__global__ __launch_bounds__(256) void k_chunk_out(
    const float* __restrict__ Qf, const float* __restrict__ Kf,
    const float* __restrict__ Vx, const float* __restrict__ S,
    float* __restrict__ Out)
{
  const int c  = blockIdx.x & (NC - 1);
  const int bh = blockIdx.x >> 4;
  const int n  = bh >> 3;
  const int h  = bh & 7;
  const int t0 = c * CHUNK;
  const int tid = threadIdx.x;
  const int ty = tid >> 4, tx = tid & 15;

  __shared__ float P[FDIM][68];      // 34816 B (68 keeps float4 rows 16B-aligned)
  __shared__ float Sc[CHUNK][EV];    // 16640 B
  __shared__ float Den[CHUNK];       //   256 B

  // phase 1: exclusive prefix of chunk states into LDS
  for (int i = tid; i < FDIM * EV; i += 256) {
    const int f = i / EV;
    const int e = i - f * EV;
    float s = 0.0f;
    const float* Sp = &S[((size_t)(bh * NC) * FDIM + f) * EV + e];
    for (int cc = 0; cc < c; ++cc) s += Sp[(size_t)cc * FDIM * EV];
    P[f][e] = s;
  }

  // phase 2: intra-chunk scores (registers; Qf/Kf streamed via L1)
  const float* Qb = &Qf[((size_t)bh * LSEQ + t0) * FDIM];
  const float* Kb = &Kf[((size_t)bh * LSEQ + t0) * FDIM];
  float acc[4][4] = {};
  for (int f = 0; f < FDIM; f += 4) {
    float qr[4][4], kr[4][4];
#pragma unroll
    for (int i = 0; i < 4; ++i) {
      const float4 q4 = *(const float4*)&Qb[((ty << 2) + i) * FDIM + f];
      qr[i][0] = q4.x; qr[i][1] = q4.y; qr[i][2] = q4.z; qr[i][3] = q4.w;
      const float4 k4 = *(const float4*)&Kb[((tx << 2) + i) * FDIM + f];
      kr[i][0] = k4.x; kr[i][1] = k4.y; kr[i][2] = k4.z; kr[i][3] = k4.w;
    }
#pragma unroll
    for (int u = 0; u < 4; ++u)
#pragma unroll
      for (int i = 0; i < 4; ++i)
#pragma unroll
        for (int j = 0; j < 4; ++j)
          acc[i][j] = fmaf(qr[i][u], kr[j][u], acc[i][j]);
  }
#pragma unroll
  for (int i = 0; i < 4; ++i)
#pragma unroll
    for (int j = 0; j < 4; ++j) {
      const int m = (ty << 2) + i, t = (tx << 2) + j;
      Sc[m][t] = (t <= m) ? acc[i][j] : 0.0f;
    }
  __syncthreads();

  // phase 3a: denominator per row (e=64 column)
  if (tid < CHUNK) {
    const int m = tid;
    float s = 0.0f;
    for (int f = 0; f < FDIM; ++f) s = fmaf(Qb[m * FDIM + f], P[f][64], s);
    for (int t = 0; t < CHUNK; ++t) s += Sc[m][t];
    Den[m] = s;
  }
  __syncthreads();

  // phase 3b: numerator tiles (4 rows x 4 e-cols per thread; e = 4*tx..)
  float o[4][4] = {};
  for (int f = 0; f < FDIM; f += 4) {
    float qr[4][4];
#pragma unroll
    for (int i = 0; i < 4; ++i) {
      const float4 q4 = *(const float4*)&Qb[((ty << 2) + i) * FDIM + f];
      qr[i][0] = q4.x; qr[i][1] = q4.y; qr[i][2] = q4.z; qr[i][3] = q4.w;
    }
#pragma unroll
    for (int u = 0; u < 4; ++u) {
      const float4 p4 = *(const float4*)&P[f + u][tx << 2];
      const float pv[4] = {p4.x, p4.y, p4.z, p4.w};
#pragma unroll
      for (int i = 0; i < 4; ++i)
#pragma unroll
        for (int j = 0; j < 4; ++j)
          o[i][j] = fmaf(qr[i][u], pv[j], o[i][j]);
    }
  }
  const float* Vb = &Vx[((size_t)bh * LSEQ + t0) * HD];
  for (int t = 0; t < CHUNK; ++t) {
    const float4 v4 = *(const float4*)&Vb[t * HD + (tx << 2)];
    const float vv[4] = {v4.x, v4.y, v4.z, v4.w};
    float sm[4];
#pragma unroll
    for (int i = 0; i < 4; ++i) sm[i] = Sc[(ty << 2) + i][t];
#pragma unroll
    for (int i = 0; i < 4; ++i)
#pragma unroll
      for (int j = 0; j < 4; ++j)
        o[i][j] = fmaf(sm[i], vv[j], o[i][j]);
  }
#pragma unroll
  for (int i = 0; i < 4; ++i) {
    const int m = (ty << 2) + i;
    const float r = 1.0f / Den[m];
    float4 res;
    res.x = o[i][0] * r; res.y = o[i][1] * r; res.z = o[i][2] * r; res.w = o[i][3] * r;
    *(float4*)&Out[((size_t)(n * LSEQ + t0 + m)) * DD + h * HD + (tx << 2)] = res;
  }
}

// ---------------------------------------------------------------------------
extern "C" void kernel_launch(void* const* d_in, const int* in_sizes, int n_in,
                              void* d_out, int out_size, void* d_ws, size_t ws_size,
                              hipStream_t stream) {
  (void)in_sizes; (void)n_in; (void)out_size; (void)ws_size;
  const float* query  = (const float*)d_in[0];
  const float* keyseq = (const float*)d_in[1];
  const float* Wq     = (const float*)d_in[2];
  const float* Wk     = (const float*)d_in[3];
  const float* Wv     = (const float*)d_in[4];
  const float* pc     = (const float*)d_in[5];  // position_coeffs (H,d)
  const float* pw     = (const float*)d_in[6];  // position_weight (H,d,1)
  const float* pb     = (const float*)d_in[7];  // position_bias (H,d)
  float* out = (float*)d_out;

  float* ws = (float*)d_ws;
  float* Qf = ws;                                   // 16*1024*128 = 2,097,152 f
  float* Kf = Qf + (size_t)NBH * LSEQ * FDIM;       // 2,097,152 f
  float* Vx = Kf + (size_t)NBH * LSEQ * FDIM;       // 1,048,576 f
  float* S  = Vx + (size_t)NBH * LSEQ * HD;         // 16*16*128*65 = 2,129,920 f
  // total ws: 29.5 MB

  k_proj_q  <<<256, 256, 0, stream>>>(query,  Wq, pw, pb, pc, Qf);
  k_proj_kv <<<512, 256, 0, stream>>>(keyseq, Wk, Wv, pw, Kf, Vx);
  k_chunk_sums<<<NBH * NC, 256, 0, stream>>>(Kf, Vx, S);
  k_chunk_out <<<NBH * NC, 256, 0, stream>>>(Qf, Kf, Vx, S, out);
}

// Round 2
// 209.580 us; speedup vs baseline: 1.4749x; 1.4749x over previous
//
#include <hip/hip_runtime.h>
#include <cmath>

// Problem constants (from reference): N=2, Lq=Lk=1024, H=8, d=64, P=1, D=512
#define NB    2
#define LSEQ  1024
#define NH    8
#define HD    64
#define DD    512    // NH*HD
#define FDIM  128    // 2*HD  (cos|sin features)
#define EV    65     // HD + 1 (values + denominator unit column)
#define CHUNK 64
#define NC    16     // LSEQ / CHUNK
#define NBH   16     // NB*NH

__device__ __forceinline__ float softplusf(float x) {
  // jax.nn.softplus == logaddexp(x, 0) == max(x,0) + log1p(exp(-|x|))
  return fmaxf(x, 0.0f) + log1pf(expf(-fabsf(x)));
}

// ---------------------------------------------------------------------------
// K1: q projection GEMM + softplus + Fourier feature expansion
// ---------------------------------------------------------------------------
__global__ __launch_bounds__(256) void k_proj_q(
    const float* __restrict__ X, const float* __restrict__ Wq,
    const float* __restrict__ pw, const float* __restrict__ pb,
    const float* __restrict__ pc, float* __restrict__ Qf)
{
  __shared__ float As[16][64];  // [k][m] transposed for float4 fragment reads
  __shared__ float Bs[16][64];  // [k][e]
  const int m0 = (blockIdx.x >> 3) << 6;   // 32 m-tiles
  const int e0 = (blockIdx.x & 7) << 6;    // 8 e-tiles
  const int tid = threadIdx.x;
  const int ty = tid >> 4, tx = tid & 15;
  const int srow = tid >> 2;               // 0..63 staging row
  const int sc4  = (tid & 3) << 2;         // 0,4,8,12 staging k-offset
  float acc[4][4] = {};
  const float* Arow = &X [(size_t)(m0 + srow) * DD + sc4];
  const float* Brow = &Wq[(size_t)(e0 + srow) * DD + sc4];
  for (int k0 = 0; k0 < DD; k0 += 16) {
    const float4 a = *(const float4*)(Arow + k0);
    const float4 b = *(const float4*)(Brow + k0);
    __syncthreads();
    As[sc4+0][srow] = a.x; As[sc4+1][srow] = a.y; As[sc4+2][srow] = a.z; As[sc4+3][srow] = a.w;
    Bs[sc4+0][srow] = b.x; Bs[sc4+1][srow] = b.y; Bs[sc4+2][srow] = b.z; Bs[sc4+3][srow] = b.w;
    __syncthreads();
#pragma unroll
    for (int kk = 0; kk < 16; ++kk) {
      const float4 a4 = *(const float4*)&As[kk][ty << 2];
      const float4 b4 = *(const float4*)&Bs[kk][tx << 2];
      const float av[4] = {a4.x, a4.y, a4.z, a4.w};
      const float bv[4] = {b4.x, b4.y, b4.z, b4.w};
#pragma unroll
      for (int i = 0; i < 4; ++i)
#pragma unroll
        for (int j = 0; j < 4; ++j)
          acc[i][j] = fmaf(av[i], bv[j], acc[i][j]);
    }
  }
#pragma unroll
  for (int i = 0; i < 4; ++i) {
    const int m = m0 + (ty << 2) + i;
    const int n = m >> 10;
    const int l = m & 1023;
#pragma unroll
    for (int j = 0; j < 4; ++j) {
      const int e  = e0 + (tx << 2) + j;
      const int h  = e >> 6;
      const int jj = e & 63;
      const float v = softplusf(acc[i][j]);
      float sn, cs;
      sincosf(fmaf((float)l, pw[e], pb[e]), &sn, &cs);
      const float vc = v * pc[e];
      float* dst = &Qf[((size_t)(n * NH + h) * LSEQ + l) * FDIM + jj];
      dst[0]  = vc * cs;
      dst[64] = vc * sn;
    }
  }
}

// ---------------------------------------------------------------------------
// K2: k and v projections. e-tiles 0..7 -> Wk path (softplus+features->Kf),
// e-tiles 8..15 -> Wv path (plain -> Vx).
// ---------------------------------------------------------------------------
__global__ __launch_bounds__(256) void k_proj_kv(
    const float* __restrict__ X, const float* __restrict__ Wk,
    const float* __restrict__ Wv, const float* __restrict__ pw,
    float* __restrict__ Kf, float* __restrict__ Vx)
{
  __shared__ float As[16][64];
  __shared__ float Bs[16][64];
  const int m0 = (blockIdx.x >> 4) << 6;   // 32 m-tiles
  const int nt = blockIdx.x & 15;          // 16 e-tiles (8 for Wk, 8 for Wv)
  const int e0 = nt << 6;
  const bool vmode = (e0 >= DD);
  const float* W = vmode ? (Wv + (size_t)(e0 - DD) * DD) : (Wk + (size_t)e0 * DD);
  const int tid = threadIdx.x;
  const int ty = tid >> 4, tx = tid & 15;
  const int srow = tid >> 2;
  const int sc4  = (tid & 3) << 2;
  float acc[4][4] = {};
  const float* Arow = &X[(size_t)(m0 + srow) * DD + sc4];
  const float* Brow = &W[(size_t)srow * DD + sc4];
  for (int k0 = 0; k0 < DD; k0 += 16) {
    const float4 a = *(const float4*)(Arow + k0);
    const float4 b = *(const float4*)(Brow + k0);
    __syncthreads();
    As[sc4+0][srow] = a.x; As[sc4+1][srow] = a.y; As[sc4+2][srow] = a.z; As[sc4+3][srow] = a.w;
    Bs[sc4+0][srow] = b.x; Bs[sc4+1][srow] = b.y; Bs[sc4+2][srow] = b.z; Bs[sc4+3][srow] = b.w;
    __syncthreads();
#pragma unroll
    for (int kk = 0; kk < 16; ++kk) {
      const float4 a4 = *(const float4*)&As[kk][ty << 2];
      const float4 b4 = *(const float4*)&Bs[kk][tx << 2];
      const float av[4] = {a4.x, a4.y, a4.z, a4.w};
      const float bv[4] = {b4.x, b4.y, b4.z, b4.w};
#pragma unroll
      for (int i = 0; i < 4; ++i)
#pragma unroll
        for (int j = 0; j < 4; ++j)
          acc[i][j] = fmaf(av[i], bv[j], acc[i][j]);
    }
  }
#pragma unroll
  for (int i = 0; i < 4; ++i) {
    const int m = m0 + (ty << 2) + i;
    const int n = m >> 10;
    const int l = m & 1023;
#pragma unroll
    for (int j = 0; j < 4; ++j) {
      if (!vmode) {
        const int e  = e0 + (tx << 2) + j;
        const int h  = e >> 6;
        const int jj = e & 63;
        const float v = softplusf(acc[i][j]);
        float sn, cs;
        sincosf((float)l * pw[e], &sn, &cs);
        float* dst = &Kf[((size_t)(n * NH + h) * LSEQ + l) * FDIM + jj];
        dst[0]  = v * cs;
        dst[64] = v * sn;
      } else {
        const int e  = e0 - DD + (tx << 2) + j;
        const int h  = e >> 6;
        const int jj = e & 63;
        Vx[((size_t)(n * NH + h) * LSEQ + l) * HD + jj] = acc[i][j];
      }
    }
  }
}

// ---------------------------------------------------------------------------
// K3: per-chunk state sums. S[bh*NC+c][f][e] = sum_{t in chunk} Kf[t][f]*Vext[t][e]
// where Vext[:,64] = 1 (denominator column).
// ---------------------------------------------------------------------------
__global__ __launch_bounds__(256) void k_chunk_sums(
    const float* __restrict__ Kf, const float* __restrict__ Vx,
    float* __restrict__ S)
{
  const int c  = blockIdx.x & (NC - 1);
  const int bh = blockIdx.x >> 4;
  const int t0 = c * CHUNK;
  const int tid = threadIdx.x;
  __shared__ float Ks[CHUNK][FDIM];  // 32 KB
  __shared__ float Vs[CHUNK][HD];    // 16 KB
  for (int i = tid; i < CHUNK * (FDIM / 4); i += 256) {
    const int r = i >> 5, c4 = (i & 31) << 2;
    *(float4*)&Ks[r][c4] = *(const float4*)&Kf[((size_t)bh * LSEQ + t0 + r) * FDIM + c4];
  }
  for (int i = tid; i < CHUNK * (HD / 4); i += 256) {
    const int r = i >> 4, c4 = (i & 15) << 2;
    *(float4*)&Vs[r][c4] = *(const float4*)&Vx[((size_t)bh * LSEQ + t0 + r) * HD + c4];
  }
  __syncthreads();
  float* Sb = &S[(size_t)blockIdx.x * FDIM * EV];
  for (int task = tid; task < 32 * 17; task += 256) {
    const int ft = task & 31;          // f-tile (4 wide)
    const int et = task >> 5;          // e-tile (4 wide), et==16 -> unit column
    const int f0 = ft << 2;
    if (et == 16) {
      float s[4] = {};
      for (int t = 0; t < CHUNK; ++t) {
        const float4 k4 = *(const float4*)&Ks[t][f0];
        s[0] += k4.x; s[1] += k4.y; s[2] += k4.z; s[3] += k4.w;
      }
#pragma unroll
      for (int u = 0; u < 4; ++u) Sb[(f0 + u) * EV + 64] = s[u];
    } else {
      const int e0 = et << 2;
      float a[4][4] = {};
      for (int t = 0; t < CHUNK; ++t) {
        const float4 k4 = *(const float4*)&Ks[t][f0];
        const float4 v4 = *(const float4*)&Vs[t][e0];
        const float kv[4] = {k4.x, k4.y, k4.z, k4.w};
        const float vv[4] = {v4.x, v4.y, v4.z, v4.w};
#pragma unroll
        for (int i = 0; i < 4; ++i)
#pragma unroll
          for (int j = 0; j < 4; ++j)
            a[i][j] = fmaf(kv[i], vv[j], a[i][j]);
      }
#pragma unroll
      for (int i = 0; i < 4; ++i)
#pragma unroll
        for (int j = 0; j < 4; ++j)
          Sb[(f0 + i) * EV + e0 + j] = a[i][j];
    }
  }
}

// ---------------------------------------------------------------------------
// K3.5: in-place exclusive prefix scan over the NC chunk states per bh.
// Block = (bh, f-group of 32 rows). Each thread owns entries; loads all NC
// values with INDEPENDENT (pipelined) loads, writes back exclusive prefix.
// After this kernel, S[bh*NC+c] holds sum_{cc<c} S_orig[bh*NC+cc].
// ---------------------------------------------------------------------------
__global__ __launch_bounds__(256) void k_scan(float* __restrict__ S)
{
  const int bh = blockIdx.x >> 2;
  const int fg = blockIdx.x & 3;           // f-group of 32 rows
  float* Sb = S + (size_t)bh * NC * FDIM * EV + (size_t)fg * 32 * EV;
  const size_t cs = (size_t)FDIM * EV;     // chunk stride
  for (int i = threadIdx.x; i < 32 * EV; i += 256) {
    float* p = Sb + i;
    float v[NC];
#pragma unroll
    for (int c = 0; c < NC; ++c) v[c] = p[c * cs];
    float s = 0.0f;
#pragma unroll
    for (int c = 0; c < NC; ++c) { const float t = v[c]; p[c * cs] = s; s += t; }
  }
}

// ---------------------------------------------------------------------------
// K4: per-chunk output.
//   P   = exclusive prefix of chunk states (now precomputed; coalesced load)
//   Sc  = tril(Qf_chunk @ Kf_chunk^T)          (LDS)
//   out = (Qf@P + Sc@Vext);  attn = num/den;  scatter to (n,l,h*64+e)
// ---------------------------------------------------------------------------
__global__ __launch_bounds__(256) void k_chunk_out(
    const float* __restrict__ Qf, const float* __restrict__ Kf,
    const float* __restrict__ Vx, const float* __restrict__ S,
    float* __restrict__ Out)
{
  const int c  = blockIdx.x & (NC - 1);
  const int bh = blockIdx.x >> 4;
  const int n  = bh >> 3;
  const int h  = bh & 7;
  const int t0 = c * CHUNK;
  const int tid = threadIdx.x;
  const int ty = tid >> 4, tx = tid & 15;

  __shared__ float P[FDIM][68];      // 34816 B (68 keeps float4 rows 16B-aligned)
  __shared__ float Sc[CHUNK][EV];    // 16640 B
  __shared__ float Den[CHUNK];       //   256 B

  // phase 1: coalesced parallel load of the precomputed prefix state
  {
    const float* Pg = &S[(size_t)(bh * NC + c) * FDIM * EV];
    for (int i = tid; i < FDIM * EV; i += 256) {
      const int f = i / EV;
      const int e = i - f * EV;
      P[f][e] = Pg[i];
    }
  }

  // phase 2: intra-chunk scores (registers; Qf/Kf streamed via L1)
  const float* Qb = &Qf[((size_t)bh * LSEQ + t0) * FDIM];
  const float* Kb = &Kf[((size_t)bh * LSEQ + t0) * FDIM];
  float acc[4][4] = {};
  for (int f = 0; f < FDIM; f += 4) {
    float qr[4][4], kr[4][4];
#pragma unroll
    for (int i = 0; i < 4; ++i) {
      const float4 q4 = *(const float4*)&Qb[((ty << 2) + i) * FDIM + f];
      qr[i][0] = q4.x; qr[i][1] = q4.y; qr[i][2] = q4.z; qr[i][3] = q4.w;
      const float4 k4 = *(const float4*)&Kb[((tx << 2) + i) * FDIM + f];
      kr[i][0] = k4.x; kr[i][1] = k4.y; kr[i][2] = k4.z; kr[i][3] = k4.w;
    }
#pragma unroll
    for (int u = 0; u < 4; ++u)
#pragma unroll
      for (int i = 0; i < 4; ++i)
#pragma unroll
        for (int j = 0; j < 4; ++j)
          acc[i][j] = fmaf(qr[i][u], kr[j][u], acc[i][j]);
  }
#pragma unroll
  for (int i = 0; i < 4; ++i)
#pragma unroll
    for (int j = 0; j < 4; ++j) {
      const int m = (ty << 2) + i, t = (tx << 2) + j;
      Sc[m][t] = (t <= m) ? acc[i][j] : 0.0f;
    }
  __syncthreads();

  // phase 3a: denominator per row (e=64 column)
  if (tid < CHUNK) {
    const int m = tid;
    float s = 0.0f;
    for (int f = 0; f < FDIM; ++f) s = fmaf(Qb[m * FDIM + f], P[f][64], s);
    for (int t = 0; t < CHUNK; ++t) s += Sc[m][t];
    Den[m] = s;
  }
  __syncthreads();

  // phase 3b: numerator tiles (4 rows x 4 e-cols per thread; e = 4*tx..)
  float o[4][4] = {};
  for (int f = 0; f < FDIM; f += 4) {
    float qr[4][4];
#pragma unroll
    for (int i = 0; i < 4; ++i) {
      const float4 q4 = *(const float4*)&Qb[((ty << 2) + i) * FDIM + f];
      qr[i][0] = q4.x; qr[i][1] = q4.y; qr[i][2] = q4.z; qr[i][3] = q4.w;
    }
#pragma unroll
    for (int u = 0; u < 4; ++u) {
      const float4 p4 = *(const float4*)&P[f + u][tx << 2];
      const float pv[4] = {p4.x, p4.y, p4.z, p4.w};
#pragma unroll
      for (int i = 0; i < 4; ++i)
#pragma unroll
        for (int j = 0; j < 4; ++j)
          o[i][j] = fmaf(qr[i][u], pv[j], o[i][j]);
    }
  }
  const float* Vb = &Vx[((size_t)bh * LSEQ + t0) * HD];
  for (int t = 0; t < CHUNK; ++t) {
    const float4 v4 = *(const float4*)&Vb[t * HD + (tx << 2)];
    const float vv[4] = {v4.x, v4.y, v4.z, v4.w};
    float sm[4];
#pragma unroll
    for (int i = 0; i < 4; ++i) sm[i] = Sc[(ty << 2) + i][t];
#pragma unroll
    for (int i = 0; i < 4; ++i)
#pragma unroll
      for (int j = 0; j < 4; ++j)
        o[i][j] = fmaf(sm[i], vv[j], o[i][j]);
  }
#pragma unroll
  for (int i = 0; i < 4; ++i) {
    const int m = (ty << 2) + i;
    const float r = 1.0f / Den[m];
    float4 res;
    res.x = o[i][0] * r; res.y = o[i][1] * r; res.z = o[i][2] * r; res.w = o[i][3] * r;
    *(float4*)&Out[((size_t)(n * LSEQ + t0 + m)) * DD + h * HD + (tx << 2)] = res;
  }
}

// ---------------------------------------------------------------------------
extern "C" void kernel_launch(void* const* d_in, const int* in_sizes, int n_in,
                              void* d_out, int out_size, void* d_ws, size_t ws_size,
                              hipStream_t stream) {
  (void)in_sizes; (void)n_in; (void)out_size; (void)ws_size;
  const float* query  = (const float*)d_in[0];
  const float* keyseq = (const float*)d_in[1];
  const float* Wq     = (const float*)d_in[2];
  const float* Wk     = (const float*)d_in[3];
  const float* Wv     = (const float*)d_in[4];
  const float* pc     = (const float*)d_in[5];  // position_coeffs (H,d)
  const float* pw     = (const float*)d_in[6];  // position_weight (H,d,1)
  const float* pb     = (const float*)d_in[7];  // position_bias (H,d)
  float* out = (float*)d_out;

  float* ws = (float*)d_ws;
  float* Qf = ws;                                   // 16*1024*128 = 2,097,152 f
  float* Kf = Qf + (size_t)NBH * LSEQ * FDIM;       // 2,097,152 f
  float* Vx = Kf + (size_t)NBH * LSEQ * FDIM;       // 1,048,576 f
  float* S  = Vx + (size_t)NBH * LSEQ * HD;         // 16*16*128*65 = 2,129,920 f
  // total ws: 29.5 MB

  k_proj_q  <<<256, 256, 0, stream>>>(query,  Wq, pw, pb, pc, Qf);
  k_proj_kv <<<512, 256, 0, stream>>>(keyseq, Wk, Wv, pw, Kf, Vx);
  k_chunk_sums<<<NBH * NC, 256, 0, stream>>>(Kf, Vx, S);
  k_scan      <<<NBH * 4,  256, 0, stream>>>(S);
  k_chunk_out <<<NBH * NC, 256, 0, stream>>>(Qf, Kf, Vx, S, out);
}

// Round 3
// 166.193 us; speedup vs baseline: 1.8600x; 1.2611x over previous
//
#include <hip/hip_runtime.h>
#include <cmath>

// Problem constants (from reference): N=2, Lq=Lk=1024, H=8, d=64, P=1, D=512
#define NB    2
#define LSEQ  1024
#define NH    8
#define HD    64
#define DD    512    // NH*HD
#define FDIM  128    // 2*HD  (cos|sin features)
#define EV    65     // HD + 1 (values + denominator unit column)
#define CHUNK 64
#define NC    16     // LSEQ / CHUNK
#define NBH   16     // NB*NH

typedef short short8 __attribute__((ext_vector_type(8)));   // 8 bf16 (4 VGPRs)
typedef float floatx4 __attribute__((ext_vector_type(4)));  // MFMA C/D frag

__device__ __forceinline__ float softplusf(float x) {
  // jax.nn.softplus == logaddexp(x, 0) == max(x,0) + log1p(exp(-|x|))
  return fmaxf(x, 0.0f) + log1pf(expf(-fabsf(x)));
}

__device__ __forceinline__ unsigned short f2bf(float f) {
  // round-to-nearest-even fp32 -> bf16 (inputs are finite normals)
  unsigned u = __float_as_uint(f);
  u += 0x7fffu + ((u >> 16) & 1u);
  return (unsigned short)(u >> 16);
}

__device__ __forceinline__ short8 cvt8(float4 a, float4 b) {
  short8 r;
  r[0] = (short)f2bf(a.x); r[1] = (short)f2bf(a.y);
  r[2] = (short)f2bf(a.z); r[3] = (short)f2bf(a.w);
  r[4] = (short)f2bf(b.x); r[5] = (short)f2bf(b.y);
  r[6] = (short)f2bf(b.z); r[7] = (short)f2bf(b.w);
  return r;
}

// ---------------------------------------------------------------------------
// K1: q projection via bf16 MFMA + softplus + Fourier feature expansion.
// C[m,e] = sum_d X[m,d]*Wq[e,d]  (both operands K-major -> B^T GEMM form).
// Block: 64x64 tile, 4 waves; wave = 1 m-tile x 4 e-tiles of 16x16x32 MFMA.
// ---------------------------------------------------------------------------
__global__ __launch_bounds__(256) void k_proj_q(
    const float* __restrict__ X, const float* __restrict__ Wq,
    const float* __restrict__ pw, const float* __restrict__ pb,
    const float* __restrict__ pc, float* __restrict__ Qf)
{
  __shared__ short Al[64][32];   // [m][k] bf16, 4 KB
  __shared__ short Bl[64][32];   // [e][k] bf16, 4 KB
  const int m0 = (blockIdx.x >> 3) << 6;   // 32 m-tiles
  const int e0 = (blockIdx.x & 7) << 6;    // 8 e-tiles
  const int tid  = threadIdx.x;
  const int r    = tid >> 2;               // staging row 0..63
  const int ko   = (tid & 3) << 3;         // staging k-offset 0,8,16,24
  const int wave = tid >> 6, lane = tid & 63;
  const int quad = lane >> 4, lm = lane & 15;
  const float* Ag = X  + (size_t)(m0 + r) * DD + ko;
  const float* Bg = Wq + (size_t)(e0 + r) * DD + ko;
  floatx4 acc[4] = {};
  for (int k0 = 0; k0 < DD; k0 += 32) {
    const float4 a0 = *(const float4*)(Ag + k0);
    const float4 a1 = *(const float4*)(Ag + k0 + 4);
    const float4 b0 = *(const float4*)(Bg + k0);
    const float4 b1 = *(const float4*)(Bg + k0 + 4);
    __syncthreads();
    *(short8*)&Al[r][ko] = cvt8(a0, a1);
    *(short8*)&Bl[r][ko] = cvt8(b0, b1);
    __syncthreads();
    const short8 af = *(const short8*)&Al[(wave << 4) + lm][quad << 3];
#pragma unroll
    for (int t = 0; t < 4; ++t) {
      const short8 bf = *(const short8*)&Bl[(t << 4) + lm][quad << 3];
      acc[t] = __builtin_amdgcn_mfma_f32_16x16x32_bf16(af, bf, acc[t], 0, 0, 0);
    }
  }
  // epilogue: softplus + sincos features, scatter to [bh][l][f]
#pragma unroll
  for (int t = 0; t < 4; ++t) {
    const int e  = e0 + (t << 4) + lm;
    const int h  = e >> 6, jj = e & 63;
    const float pwv = pw[e], pbv = pb[e], pcv = pc[e];
#pragma unroll
    for (int rg = 0; rg < 4; ++rg) {
      const int m = m0 + (wave << 4) + (quad << 2) + rg;
      const int n = m >> 10, l = m & 1023;
      const float v = softplusf(acc[t][rg]) * pcv;
      float sn, cs;
      sincosf(fmaf((float)l, pwv, pbv), &sn, &cs);
      float* dst = &Qf[((size_t)(n * NH + h) * LSEQ + l) * FDIM + jj];
      dst[0]  = v * cs;
      dst[64] = v * sn;
    }
  }
}

// ---------------------------------------------------------------------------
// K2: k and v projections via bf16 MFMA. e-tiles 0..7 -> Wk path
// (softplus+features->Kf), e-tiles 8..15 -> Wv path (plain -> Vx).
// ---------------------------------------------------------------------------
__global__ __launch_bounds__(256) void k_proj_kv(
    const float* __restrict__ X, const float* __restrict__ Wk,
    const float* __restrict__ Wv, const float* __restrict__ pw,
    float* __restrict__ Kf, float* __restrict__ Vx)
{
  __shared__ short Al[64][32];
  __shared__ short Bl[64][32];
  const int m0 = (blockIdx.x >> 4) << 6;   // 32 m-tiles
  const int nt = blockIdx.x & 15;          // 16 e-tiles (8 Wk, 8 Wv)
  const int e0 = nt << 6;
  const bool vmode = (e0 >= DD);
  const float* W = vmode ? (Wv + (size_t)(e0 - DD) * DD) : (Wk + (size_t)e0 * DD);
  const int tid  = threadIdx.x;
  const int r    = tid >> 2;
  const int ko   = (tid & 3) << 3;
  const int wave = tid >> 6, lane = tid & 63;
  const int quad = lane >> 4, lm = lane & 15;
  const float* Ag = X + (size_t)(m0 + r) * DD + ko;
  const float* Bg = W + (size_t)r * DD + ko;
  floatx4 acc[4] = {};
  for (int k0 = 0; k0 < DD; k0 += 32) {
    const float4 a0 = *(const float4*)(Ag + k0);
    const float4 a1 = *(const float4*)(Ag + k0 + 4);
    const float4 b0 = *(const float4*)(Bg + k0);
    const float4 b1 = *(const float4*)(Bg + k0 + 4);
    __syncthreads();
    *(short8*)&Al[r][ko] = cvt8(a0, a1);
    *(short8*)&Bl[r][ko] = cvt8(b0, b1);
    __syncthreads();
    const short8 af = *(const short8*)&Al[(wave << 4) + lm][quad << 3];
#pragma unroll
    for (int t = 0; t < 4; ++t) {
      const short8 bf = *(const short8*)&Bl[(t << 4) + lm][quad << 3];
      acc[t] = __builtin_amdgcn_mfma_f32_16x16x32_bf16(af, bf, acc[t], 0, 0, 0);
    }
  }
#pragma unroll
  for (int t = 0; t < 4; ++t) {
    const int eg = e0 + (t << 4) + lm;              // global e in [0,1024)
    if (!vmode) {
      const int h = eg >> 6, jj = eg & 63;
      const float pwv = pw[eg];
#pragma unroll
      for (int rg = 0; rg < 4; ++rg) {
        const int m = m0 + (wave << 4) + (quad << 2) + rg;
        const int n = m >> 10, l = m & 1023;
        const float v = softplusf(acc[t][rg]);
        float sn, cs;
        sincosf((float)l * pwv, &sn, &cs);
        float* dst = &Kf[((size_t)(n * NH + h) * LSEQ + l) * FDIM + jj];
        dst[0]  = v * cs;
        dst[64] = v * sn;
      }
    } else {
      const int e = eg - DD;
      const int h = e >> 6, jj = e & 63;
#pragma unroll
      for (int rg = 0; rg < 4; ++rg) {
        const int m = m0 + (wave << 4) + (quad << 2) + rg;
        const int n = m >> 10, l = m & 1023;
        Vx[((size_t)(n * NH + h) * LSEQ + l) * HD + jj] = acc[t][rg];
      }
    }
  }
}

// ---------------------------------------------------------------------------
// K3: per-chunk state sums. S[bh*NC+c][f][e] = sum_{t in chunk} Kf[t][f]*Vext[t][e]
// where Vext[:,64] = 1 (denominator column).
// ---------------------------------------------------------------------------
__global__ __launch_bounds__(256) void k_chunk_sums(
    const float* __restrict__ Kf, const float* __restrict__ Vx,
    float* __restrict__ S)
{
  const int c  = blockIdx.x & (NC - 1);
  const int bh = blockIdx.x >> 4;
  const int t0 = c * CHUNK;
  const int tid = threadIdx.x;
  __shared__ float Ks[CHUNK][FDIM];  // 32 KB
  __shared__ float Vs[CHUNK][HD];    // 16 KB
  for (int i = tid; i < CHUNK * (FDIM / 4); i += 256) {
    const int r = i >> 5, c4 = (i & 31) << 2;
    *(float4*)&Ks[r][c4] = *(const float4*)&Kf[((size_t)bh * LSEQ + t0 + r) * FDIM + c4];
  }
  for (int i = tid; i < CHUNK * (HD / 4); i += 256) {
    const int r = i >> 4, c4 = (i & 15) << 2;
    *(float4*)&Vs[r][c4] = *(const float4*)&Vx[((size_t)bh * LSEQ + t0 + r) * HD + c4];
  }
  __syncthreads();
  float* Sb = &S[(size_t)blockIdx.x * FDIM * EV];
  for (int task = tid; task < 32 * 17; task += 256) {
    const int ft = task & 31;          // f-tile (4 wide)
    const int et = task >> 5;          // e-tile (4 wide), et==16 -> unit column
    const int f0 = ft << 2;
    if (et == 16) {
      float s[4] = {};
      for (int t = 0; t < CHUNK; ++t) {
        const float4 k4 = *(const float4*)&Ks[t][f0];
        s[0] += k4.x; s[1] += k4.y; s[2] += k4.z; s[3] += k4.w;
      }
#pragma unroll
      for (int u = 0; u < 4; ++u) Sb[(f0 + u) * EV + 64] = s[u];
    } else {
      const int e0 = et << 2;
      float a[4][4] = {};
      for (int t = 0; t < CHUNK; ++t) {
        const float4 k4 = *(const float4*)&Ks[t][f0];
        const float4 v4 = *(const float4*)&Vs[t][e0];
        const float kv[4] = {k4.x, k4.y, k4.z, k4.w};
        const float vv[4] = {v4.x, v4.y, v4.z, v4.w};
#pragma unroll
        for (int i = 0; i < 4; ++i)
#pragma unroll
          for (int j = 0; j < 4; ++j)
            a[i][j] = fmaf(kv[i], vv[j], a[i][j]);
      }
#pragma unroll
      for (int i = 0; i < 4; ++i)
#pragma unroll
        for (int j = 0; j < 4; ++j)
          Sb[(f0 + i) * EV + e0 + j] = a[i][j];
    }
  }
}

// ---------------------------------------------------------------------------
// K3.5: in-place exclusive prefix scan over the NC chunk states per bh.
// ---------------------------------------------------------------------------
__global__ __launch_bounds__(256) void k_scan(float* __restrict__ S)
{
  const int bh = blockIdx.x >> 2;
  const int fg = blockIdx.x & 3;           // f-group of 32 rows
  float* Sb = S + (size_t)bh * NC * FDIM * EV + (size_t)fg * 32 * EV;
  const size_t cs = (size_t)FDIM * EV;     // chunk stride
  for (int i = threadIdx.x; i < 32 * EV; i += 256) {
    float* p = Sb + i;
    float v[NC];
#pragma unroll
    for (int c = 0; c < NC; ++c) v[c] = p[c * cs];
    float s = 0.0f;
#pragma unroll
    for (int c = 0; c < NC; ++c) { const float t = v[c]; p[c * cs] = s; s += t; }
  }
}

// ---------------------------------------------------------------------------
// K4: per-chunk output.
//   P   = exclusive prefix of chunk states (precomputed; coalesced load)
//   Sc  = tril(Qf_chunk @ Kf_chunk^T)          (LDS)
//   out = (Qf@P + Sc@Vext);  attn = num/den;  scatter to (n,l,h*64+e)
// ---------------------------------------------------------------------------
__global__ __launch_bounds__(256) void k_chunk_out(
    const float* __restrict__ Qf, const float* __restrict__ Kf,
    const float* __restrict__ Vx, const float* __restrict__ S,
    float* __restrict__ Out)
{
  const int c  = blockIdx.x & (NC - 1);
  const int bh = blockIdx.x >> 4;
  const int n  = bh >> 3;
  const int h  = bh & 7;
  const int t0 = c * CHUNK;
  const int tid = threadIdx.x;
  const int ty = tid >> 4, tx = tid & 15;

  __shared__ float P[FDIM][68];      // 34816 B (68 keeps float4 rows 16B-aligned)
  __shared__ float Sc[CHUNK][EV];    // 16640 B
  __shared__ float Den[CHUNK];       //   256 B

  // phase 1: coalesced parallel load of the precomputed prefix state
  {
    const float* Pg = &S[(size_t)(bh * NC + c) * FDIM * EV];
    for (int i = tid; i < FDIM * EV; i += 256) {
      const int f = i / EV;
      const int e = i - f * EV;
      P[f][e] = Pg[i];
    }
  }

  // phase 2: intra-chunk scores (registers; Qf/Kf streamed via L1)
  const float* Qb = &Qf[((size_t)bh * LSEQ + t0) * FDIM];
  const float* Kb = &Kf[((size_t)bh * LSEQ + t0) * FDIM];
  float acc[4][4] = {};
  for (int f = 0; f < FDIM; f += 4) {
    float qr[4][4], kr[4][4];
#pragma unroll
    for (int i = 0; i < 4; ++i) {
      const float4 q4 = *(const float4*)&Qb[((ty << 2) + i) * FDIM + f];
      qr[i][0] = q4.x; qr[i][1] = q4.y; qr[i][2] = q4.z; qr[i][3] = q4.w;
      const float4 k4 = *(const float4*)&Kb[((tx << 2) + i) * FDIM + f];
      kr[i][0] = k4.x; kr[i][1] = k4.y; kr[i][2] = k4.z; kr[i][3] = k4.w;
    }
#pragma unroll
    for (int u = 0; u < 4; ++u)
#pragma unroll
      for (int i = 0; i < 4; ++i)
#pragma unroll
        for (int j = 0; j < 4; ++j)
          acc[i][j] = fmaf(qr[i][u], kr[j][u], acc[i][j]);
  }
#pragma unroll
  for (int i = 0; i < 4; ++i)
#pragma unroll
    for (int j = 0; j < 4; ++j) {
      const int m = (ty << 2) + i, t = (tx << 2) + j;
      Sc[m][t] = (t <= m) ? acc[i][j] : 0.0f;
    }
  __syncthreads();

  // phase 3a: denominator per row (e=64 column)
  if (tid < CHUNK) {
    const int m = tid;
    float s = 0.0f;
    for (int f = 0; f < FDIM; ++f) s = fmaf(Qb[m * FDIM + f], P[f][64], s);
    for (int t = 0; t < CHUNK; ++t) s += Sc[m][t];
    Den[m] = s;
  }
  __syncthreads();

  // phase 3b: numerator tiles (4 rows x 4 e-cols per thread; e = 4*tx..)
  float o[4][4] = {};
  for (int f = 0; f < FDIM; f += 4) {
    float qr[4][4];
#pragma unroll
    for (int i = 0; i < 4; ++i) {
      const float4 q4 = *(const float4*)&Qb[((ty << 2) + i) * FDIM + f];
      qr[i][0] = q4.x; qr[i][1] = q4.y; qr[i][2] = q4.z; qr[i][3] = q4.w;
    }
#pragma unroll
    for (int u = 0; u < 4; ++u) {
      const float4 p4 = *(const float4*)&P[f + u][tx << 2];
      const float pv[4] = {p4.x, p4.y, p4.z, p4.w};
#pragma unroll
      for (int i = 0; i < 4; ++i)
#pragma unroll
        for (int j = 0; j < 4; ++j)
          o[i][j] = fmaf(qr[i][u], pv[j], o[i][j]);
    }
  }
  const float* Vb = &Vx[((size_t)bh * LSEQ + t0) * HD];
  for (int t = 0; t < CHUNK; ++t) {
    const float4 v4 = *(const float4*)&Vb[t * HD + (tx << 2)];
    const float vv[4] = {v4.x, v4.y, v4.z, v4.w};
    float sm[4];
#pragma unroll
    for (int i = 0; i < 4; ++i) sm[i] = Sc[(ty << 2) + i][t];
#pragma unroll
    for (int i = 0; i < 4; ++i)
#pragma unroll
      for (int j = 0; j < 4; ++j)
        o[i][j] = fmaf(sm[i], vv[j], o[i][j]);
  }
#pragma unroll
  for (int i = 0; i < 4; ++i) {
    const int m = (ty << 2) + i;
    const float r = 1.0f / Den[m];
    float4 res;
    res.x = o[i][0] * r; res.y = o[i][1] * r; res.z = o[i][2] * r; res.w = o[i][3] * r;
    *(float4*)&Out[((size_t)(n * LSEQ + t0 + m)) * DD + h * HD + (tx << 2)] = res;
  }
}

// ---------------------------------------------------------------------------
extern "C" void kernel_launch(void* const* d_in, const int* in_sizes, int n_in,
                              void* d_out, int out_size, void* d_ws, size_t ws_size,
                              hipStream_t stream) {
  (void)in_sizes; (void)n_in; (void)out_size; (void)ws_size;
  const float* query  = (const float*)d_in[0];
  const float* keyseq = (const float*)d_in[1];
  const float* Wq     = (const float*)d_in[2];
  const float* Wk     = (const float*)d_in[3];
  const float* Wv     = (const float*)d_in[4];
  const float* pc     = (const float*)d_in[5];  // position_coeffs (H,d)
  const float* pw     = (const float*)d_in[6];  // position_weight (H,d,1)
  const float* pb     = (const float*)d_in[7];  // position_bias (H,d)
  float* out = (float*)d_out;

  float* ws = (float*)d_ws;
  float* Qf = ws;                                   // 16*1024*128 = 2,097,152 f
  float* Kf = Qf + (size_t)NBH * LSEQ * FDIM;       // 2,097,152 f
  float* Vx = Kf + (size_t)NBH * LSEQ * FDIM;       // 1,048,576 f
  float* S  = Vx + (size_t)NBH * LSEQ * HD;         // 16*16*128*65 = 2,129,920 f
  // total ws: 29.5 MB

  k_proj_q  <<<256, 256, 0, stream>>>(query,  Wq, pw, pb, pc, Qf);
  k_proj_kv <<<512, 256, 0, stream>>>(keyseq, Wk, Wv, pw, Kf, Vx);
  k_chunk_sums<<<NBH * NC, 256, 0, stream>>>(Kf, Vx, S);
  k_scan      <<<NBH * 4,  256, 0, stream>>>(S);
  k_chunk_out <<<NBH * NC, 256, 0, stream>>>(Qf, Kf, Vx, S, out);
}